// Round 8
// baseline (634.395 us; speedup 1.0000x reference)
//
#include <hip/hip_runtime.h>
#include <hip/hip_cooperative_groups.h>
#include <math.h>

namespace cg = cooperative_groups;

#define N_PTS 8192
#define D_FEAT 768

typedef float v2f __attribute__((ext_vector_type(2)));

// ---- wave64 reductions via DPP (row_shr 1,2,4,8 + row_bcast15, row_bcast31) ----
__device__ __forceinline__ float wred_max_f32(float x) {   // x >= 0 required (identity 0)
    int v = __float_as_int(x), o;
    o = __builtin_amdgcn_update_dpp(0, v, 0x111, 0xf, 0xf, false); v = __float_as_int(fmaxf(__int_as_float(v), __int_as_float(o)));
    o = __builtin_amdgcn_update_dpp(0, v, 0x112, 0xf, 0xf, false); v = __float_as_int(fmaxf(__int_as_float(v), __int_as_float(o)));
    o = __builtin_amdgcn_update_dpp(0, v, 0x114, 0xf, 0xf, false); v = __float_as_int(fmaxf(__int_as_float(v), __int_as_float(o)));
    o = __builtin_amdgcn_update_dpp(0, v, 0x118, 0xf, 0xf, false); v = __float_as_int(fmaxf(__int_as_float(v), __int_as_float(o)));
    o = __builtin_amdgcn_update_dpp(0, v, 0x142, 0xa, 0xf, false); v = __float_as_int(fmaxf(__int_as_float(v), __int_as_float(o)));
    o = __builtin_amdgcn_update_dpp(0, v, 0x143, 0xc, 0xf, false); v = __float_as_int(fmaxf(__int_as_float(v), __int_as_float(o)));
    return __int_as_float(__builtin_amdgcn_readlane(v, 63));
}
__device__ __forceinline__ int wred_min_i32(int x) {       // x >= 0 (identity INT_MAX)
    int v = x, o;
    o = __builtin_amdgcn_update_dpp(0x7fffffff, v, 0x111, 0xf, 0xf, false); v = (o < v) ? o : v;
    o = __builtin_amdgcn_update_dpp(0x7fffffff, v, 0x112, 0xf, 0xf, false); v = (o < v) ? o : v;
    o = __builtin_amdgcn_update_dpp(0x7fffffff, v, 0x114, 0xf, 0xf, false); v = (o < v) ? o : v;
    o = __builtin_amdgcn_update_dpp(0x7fffffff, v, 0x118, 0xf, 0xf, false); v = (o < v) ? o : v;
    o = __builtin_amdgcn_update_dpp(0x7fffffff, v, 0x142, 0xa, 0xf, false); v = (o < v) ? o : v;
    o = __builtin_amdgcn_update_dpp(0x7fffffff, v, 0x143, 0xc, 0xf, false); v = (o < v) ? o : v;
    return __builtin_amdgcn_readlane(v, 63);
}
__device__ __forceinline__ float wred_add_f32(float x) {   // identity 0
    int v = __float_as_int(x), o;
    o = __builtin_amdgcn_update_dpp(0, v, 0x111, 0xf, 0xf, false); v = __float_as_int(__int_as_float(v) + __int_as_float(o));
    o = __builtin_amdgcn_update_dpp(0, v, 0x112, 0xf, 0xf, false); v = __float_as_int(__int_as_float(v) + __int_as_float(o));
    o = __builtin_amdgcn_update_dpp(0, v, 0x114, 0xf, 0xf, false); v = __float_as_int(__int_as_float(v) + __int_as_float(o));
    o = __builtin_amdgcn_update_dpp(0, v, 0x118, 0xf, 0xf, false); v = __float_as_int(__int_as_float(v) + __int_as_float(o));
    o = __builtin_amdgcn_update_dpp(0, v, 0x142, 0xa, 0xf, false); v = __float_as_int(__int_as_float(v) + __int_as_float(o));
    o = __builtin_amdgcn_update_dpp(0, v, 0x143, 0xc, 0xf, false); v = __float_as_int(__int_as_float(v) + __int_as_float(o));
    return __int_as_float(__builtin_amdgcn_readlane(v, 63));
}

// u64 max-merge DPP step: compiler lowers the compare to one v_cmp_lt_u64.
#define DPP64_STEP(cur, ctrl, rmask)                                                        \
    {                                                                                       \
        unsigned _h = (unsigned)__builtin_amdgcn_update_dpp(0, (int)(unsigned)((cur) >> 32), ctrl, rmask, 0xf, false); \
        unsigned _l = (unsigned)__builtin_amdgcn_update_dpp(0, (int)(unsigned)(cur), ctrl, rmask, 0xf, false);         \
        unsigned long long _o = ((unsigned long long)_h << 32) | _l;                        \
        cur = (_o > (cur)) ? _o : (cur);                                                    \
    }

// W1 GEMM k-split (phase 1): rp = t&7 owns 96-float k-chunk, jg = t>>3 owns RT rows.
#define W1_GEMM(RT)                                                            \
  {                                                                            \
    const int jg = t >> 3, rp = t & 7;                                         \
    const float* wb = W1 + (size_t)(jg * RT) * 768 + rp * 96;                  \
    float4 acc[RT][8];                                                         \
    _Pragma("unroll") for (int a = 0; a < RT; a++)                             \
      _Pragma("unroll") for (int r = 0; r < 8; r++)                            \
        acc[a][r] = make_float4(0.f, 0.f, 0.f, 0.f);                           \
    for (int s = 0; s < 96; s += 4) {                                          \
      float4 xv[8];                                                            \
      _Pragma("unroll") for (int r = 0; r < 8; r++)                            \
        xv[r] = *(const float4*)&xt[r * 772 + rp * 96 + s];                    \
      _Pragma("unroll") for (int a = 0; a < RT; a++) {                         \
        float4 wv = *(const float4*)&wb[(size_t)a * 768 + s];                  \
        _Pragma("unroll") for (int r = 0; r < 8; r++) {                        \
          acc[a][r].x = fmaf(wv.x, xv[r].x, acc[a][r].x);                      \
          acc[a][r].y = fmaf(wv.y, xv[r].y, acc[a][r].y);                      \
          acc[a][r].z = fmaf(wv.z, xv[r].z, acc[a][r].z);                      \
          acc[a][r].w = fmaf(wv.w, xv[r].w, acc[a][r].w);                      \
        }                                                                      \
      }                                                                        \
    }                                                                          \
    _Pragma("unroll") for (int a = 0; a < RT; a++)                             \
      _Pragma("unroll") for (int r = 0; r < 8; r++)                            \
        part[rp * 2048 + (jg * RT + a) * 8 + r] =                              \
            (acc[a][r].x + acc[a][r].y) + (acc[a][r].z + acc[a][r].w);         \
  }

// ---------------- ROUND 15: single cooperative kernel, 4 phases ----------------
// Non-fps time has been invariant (~214-237 us) across 6-kernel / 4-kernel /
// 256-thr / 512-thr structures => it is per-launch / inter-node overhead, not
// compute. This merges all phases into ONE dispatch with grid.sync() between.
// Phase bodies are byte-identical to the r7 kernels (same arithmetic, same
// order); LDS is overlaid through one 130 KB buffer, safe across grid.sync.
__global__ __launch_bounds__(512, 2) __attribute__((amdgpu_waves_per_eu(2)))
void mega_kernel(const float* __restrict__ feat, const float* __restrict__ coords,
                 const float* __restrict__ gW1, const float* __restrict__ gb1,
                 const float* __restrict__ gW2, const float* __restrict__ gb2,
                 const float* __restrict__ cW1, const float* __restrict__ cb1,
                 const float* __restrict__ cW2, const float* __restrict__ cb2,
                 const float* __restrict__ dW1, const float* __restrict__ db1,
                 const float* __restrict__ dW2, const float* __restrict__ db2,
                 const float* __restrict__ pW1, const float* __restrict__ pb1,
                 const float* __restrict__ pW2, const float* __restrict__ pb2,
                 const float* __restrict__ lng, const float* __restrict__ lnb,
                 float* __restrict__ out,
                 int* __restrict__ idx_all, float* __restrict__ safety_all,
                 float* __restrict__ final_all, float* __restrict__ h_buf) {
    cg::grid_group grid = cg::this_grid();
    __shared__ __align__(16) float smem[33280];   // 130 KB overlay
    const int bid = blockIdx.x;
    const int t = threadIdx.x;                    // 0..511
    const int lane = t & 63, w = t >> 6;

    // ================= phase 0: FPS + safety (blocks 0,1) =================
    if (bid < 2) {
#pragma clang fp contract(off)
        const int b = bid;
        const float* cb = coords + (size_t)b * N_PTS * 3;
        float* cbl4 = smem;                                   // 32768 floats
        unsigned long long* skey = (unsigned long long*)(smem + 32768);  // [2][8]
        int* sel = (int*)(smem + 32800);                      // 256
        float* r1s = smem + 33056, *r2s = smem + 33064;       // 8 + 8

        v2f px2[8], py2[8], pz2[8], m2p[8];
#pragma unroll
        for (int j = 0; j < 8; j++) {
            int p0 = t + (2 * j) * 512, p1 = t + (2 * j + 1) * 512;
            px2[j].x = cb[p0 * 3 + 0]; px2[j].y = cb[p1 * 3 + 0];
            py2[j].x = cb[p0 * 3 + 1]; py2[j].y = cb[p1 * 3 + 1];
            pz2[j].x = cb[p0 * 3 + 2]; pz2[j].y = cb[p1 * 3 + 2];
            m2p[j].x = INFINITY; m2p[j].y = INFINITY;
        }
#pragma unroll
        for (int j = 0; j < 8; j++) {
            int p0 = t + (2 * j) * 512, p1 = t + (2 * j + 1) * 512;
            *(float4*)&cbl4[p0 * 4] = make_float4(px2[j].x, py2[j].x, pz2[j].x, 0.f);
            *(float4*)&cbl4[p1 * 4] = make_float4(px2[j].y, py2[j].y, pz2[j].y, 0.f);
        }
        if (t == 0) sel[0] = 0;
        float lx = cb[0], ly = cb[1], lz = cb[2];   // center 0 (uniform)
        __syncthreads();

        for (int i = 1; i < 256; i++) {
            v2f Lx = {lx, lx}, Ly = {ly, ly}, Lz = {lz, lz};
#pragma unroll
            for (int j = 0; j < 8; j++) {
                v2f dx = px2[j] - Lx, dy = py2[j] - Ly, dz = pz2[j] - Lz;
                v2f d2 = dx * dx + dy * dy + dz * dz;      // ((dx^2+dy^2)+dz^2), no fma
                m2p[j] = __builtin_elementwise_min(m2p[j], d2);
            }
            v2f q[4];
#pragma unroll
            for (int j = 0; j < 4; j++) q[j] = __builtin_elementwise_max(m2p[j], m2p[j + 4]);
            q[0] = __builtin_elementwise_max(q[0], q[2]);
            q[1] = __builtin_elementwise_max(q[1], q[3]);
            q[0] = __builtin_elementwise_max(q[0], q[1]);
            float c2 = fmaxf(q[0].x, q[0].y);
            float smax = sqrtf(c2);       // hoisted: hides under match/guard
            float thi = c2 * 0.9999995f;
            int tot = 0;
            int ci[8];
#pragma unroll
            for (int j = 0; j < 8; j++) {
                bool bx = (m2p[j].x >= thi);
                bool by = (m2p[j].y >= thi);
                tot += __popcll(__ballot(bx));
                tot += __popcll(__ballot(by));
                int a  = bx ? (2 * j)     : 0x7fff;
                int bb = by ? (2 * j + 1) : 0x7fff;
                ci[j] = (a < bb) ? a : bb;
            }
#pragma unroll
            for (int j = 0; j < 4; j++) ci[j] = min(ci[j], ci[j + 4]);
            int bk = min(min(ci[0], ci[1]), min(ci[2], ci[3]));
            if (tot > 64) {               // rare wave-uniform slow path (exact)
                smax = -1.f; bk = 0;
#pragma unroll
                for (int k = 0; k < 16; k++) {
                    float mk = (k & 1) ? m2p[k >> 1].y : m2p[k >> 1].x;
                    float s = sqrtf(mk);
                    if (s > smax) { smax = s; bk = k; }
                }
            }
            int bi = t + bk * 512;
            unsigned long long key = ((unsigned long long)__float_as_uint(smax) << 32)
                                   | (unsigned)(0xFFFFFFFFu - (unsigned)bi);
            DPP64_STEP(key, 0x111, 0xf)
            DPP64_STEP(key, 0x112, 0xf)
            DPP64_STEP(key, 0x114, 0xf)
            DPP64_STEP(key, 0x118, 0xf)
            DPP64_STEP(key, 0x142, 0xa)
            DPP64_STEP(key, 0x143, 0xc)
            if (lane == 63) skey[(i & 1) * 8 + w] = key;
            __syncthreads();
            const int par = i & 1;
            unsigned long long k8 = skey[par * 8 + (lane & 7)];
            int cidx = (int)(0xFFFFFFFFu - (unsigned)k8);
            float spec = 0.f;
            if (lane < 24) spec = cbl4[cidx * 4 + (lane >> 3)];
            DPP64_STEP(k8, 0x111, 0xf)
            DPP64_STEP(k8, 0x112, 0xf)
            DPP64_STEP(k8, 0x114, 0xf)     // lane 7 = max of records 0..7
            unsigned klo = (unsigned)__builtin_amdgcn_readlane((int)(unsigned)k8, 7);
            int fbi = (int)(0xFFFFFFFFu - klo);
            int ww = (fbi & 511) >> 6;
            lx = __int_as_float(__builtin_amdgcn_readlane(__float_as_int(spec), ww));
            ly = __int_as_float(__builtin_amdgcn_readlane(__float_as_int(spec), 8 + ww));
            lz = __int_as_float(__builtin_amdgcn_readlane(__float_as_int(spec), 16 + ww));
            if (t == 0) sel[i] = fbi;
        }

        __syncthreads();
        if (t < 256) {
            int v = sel[t];
            idx_all[b * 256 + t] = v;                    // og
            if (t < 128) idx_all[512 + b * 128 + t] = v; // oc
            if (t < 64)  idx_all[768 + b * 64 + t] = v;  // od
        }
        float s1 = 0.f, s2 = 0.f;
#pragma unroll
        for (int j = 0; j < 8; j++) {
            s1 += pz2[j].x; s2 += pz2[j].x * pz2[j].x;
            s1 += pz2[j].y; s2 += pz2[j].y * pz2[j].y;
        }
        s1 = wred_add_f32(s1);
        s2 = wred_add_f32(s2);
        if (lane == 0) { r1s[w] = s1; r2s[w] = s2; }
        __syncthreads();
        float S1 = ((r1s[0] + r1s[1]) + (r1s[2] + r1s[3])) + ((r1s[4] + r1s[5]) + (r1s[6] + r1s[7]));
        float S2 = ((r2s[0] + r2s[1]) + (r2s[2] + r2s[3])) + ((r2s[4] + r2s[5]) + (r2s[6] + r2s[7]));
        float mean = S1 / 8192.0f;
        float var1 = (S2 - S1 * S1 / 8192.0f) / 8191.0f;     // ddof=1
        float scomp = 1.0f + expf(-var1 / 0.1f) * 0.9f;
        if (t < 256) {
            int p = sel[t];
            float z = cbl4[p * 4 + 2];
            safety_all[b * 256 + t] = 1.0f + (1.0f / (1.0f + expf(-((z - mean) / 5.0f)))) * 0.95f;
            if (t < 128) safety_all[512 + b * 128 + t] = scomp;
        }
    }
    grid.sync();

    // ================= phase 1: per-scale score MLP (all 112 blocks) =================
    {
        int b, c0, C, S, off;
        const float *W1, *b1, *W2, *b2;
        if (bid < 64)      { C = 256; S = 16; W1 = gW1; b1 = gb1; W2 = gW2; b2 = gb2; b = bid >> 5; c0 = (bid & 31) * 8; off = 0; }
        else if (bid < 96) { int r = bid - 64; C = 128; S = 16; W1 = cW1; b1 = cb1; W2 = cW2; b2 = cb2; b = r >> 4; c0 = (r & 15) * 8; off = 512; }
        else               { int r = bid - 96; C = 64;  S = 8;  W1 = dW1; b1 = db1; W2 = dW2; b2 = db2; b = r >> 3; c0 = (r & 7) * 8; off = 768; }
        const bool isdet = (bid >= 96);

        float* xt   = smem;                 // 6176
        float* h1s  = smem + 6176;          // 2080
        float* part = smem + 8256;          // 16384
        float* ps   = smem + 24640;         // 128
        int*   pid  = (int*)(smem + 24768); // 8
        float* dpart= smem + 24776;         // [8][8]
        float* sdens= smem + 24840;         // 8

        if (t < 8) pid[t] = idx_all[off + b * C + c0 + t];
        __syncthreads();

        if (isdet) {
#pragma clang fp contract(off)
            float cx[8], cy[8], cz[8], cc[8];
#pragma unroll
            for (int c = 0; c < 8; c++) {
                const float* cp = coords + ((size_t)b * N_PTS + pid[c]) * 3;
                cx[c] = cp[0]; cy[c] = cp[1]; cz[c] = cp[2];
                cc[c] = cx[c] * cx[c] + cy[c] * cy[c] + cz[c] * cz[c];
            }
            int cnt[8];
#pragma unroll
            for (int c = 0; c < 8; c++) cnt[c] = 0;
            const float* cbl = coords + (size_t)b * N_PTS * 3;
            for (int k = 0; k < 16; k++) {
                int q = t + k * 512;
                float x = cbl[q * 3], y = cbl[q * 3 + 1], z = cbl[q * 3 + 2];
                float pp = x * x + y * y + z * z;
#pragma unroll
                for (int c = 0; c < 8; c++) {
                    float dot = cx[c] * x + cy[c] * y + cz[c] * z;
                    float d2 = (cc[c] + pp) - 2.0f * dot;   // reference formula/order
                    if (d2 < 0.25f) cnt[c]++;
                }
            }
#pragma unroll
            for (int c = 0; c < 8; c++) {
                float s = wred_add_f32((float)cnt[c]);      // integer counts: exact
                if (lane == 0) dpart[w * 8 + c] = s;
            }
        }

        for (int r = 0; r < 8; r++) {
            const float* src = feat + ((size_t)b * N_PTS + pid[r]) * D_FEAT;
            for (int c = t; c < 768; c += 512) xt[r * 772 + c] = src[c];
        }
        __syncthreads();
        if (isdet && t < 8) {
            float tot = ((dpart[0 + t] + dpart[8 + t]) + (dpart[16 + t] + dpart[24 + t]))
                      + ((dpart[32 + t] + dpart[40 + t]) + (dpart[48 + t] + dpart[56 + t]));
            sdens[t] = 1.0f + (tot / 8192.0f) * 0.95f;
        }

        if (C == 256)      W1_GEMM(4)
        else if (C == 128) W1_GEMM(2)
        else               W1_GEMM(1)
        __syncthreads();
        for (int u = t; u < C * 8; u += 512) {
            int row = u >> 3;
            float sum = ((part[u] + part[2048 + u]) + (part[4096 + u] + part[6144 + u]))
                      + ((part[8192 + u] + part[10240 + u]) + (part[12288 + u] + part[14336 + u]))
                      + b1[row];
            h1s[(u & 7) * 260 + row] = fmaxf(sum, 0.f);
        }
        __syncthreads();

        if (t < 8 * S) {
            int r = t / S, s = t % S;
            float4 a = make_float4(0, 0, 0, 0);
            for (int k = 0; k < C; k += 4) {
                float4 wv = *(const float4*)&W2[s * C + k];
                float4 h = *(const float4*)&h1s[r * 260 + k];
                a.x = fmaf(wv.x, h.x, a.x); a.y = fmaf(wv.y, h.y, a.y);
                a.z = fmaf(wv.z, h.z, a.z); a.w = fmaf(wv.w, h.w, a.w);
            }
            float logit = (a.x + a.y) + (a.z + a.w) + b2[s];
            ps[r * 16 + s] = 1.0f / (1.0f + expf(-logit));
        }
        __syncthreads();
        if (t < 8) {
            float m = 0.f;
            for (int s = 0; s < S; s++) m += ps[t * 16 + s];
            m /= (float)S;
            float saf = isdet ? sdens[t] : safety_all[off + b * C + c0 + t];
            final_all[off + b * C + c0 + t] = m * saf;
        }
    }
    grid.sync();

    // ================= phase 2: topk + h GEMM (blocks < 96) =================
    if (bid < 96) {
        int b = bid / 48, js = bid % 48;
        int* tokp = (int*)smem;             // 40
        if (w < 3) {                        // wave w does scale w's top-k
            int sc = w;
            int C    = (sc == 0) ? 256 : (sc == 1) ? 128 : 64;
            int off  = (sc == 0) ? 0 : (sc == 1) ? 512 : 768;
            int base = (sc == 0) ? 0 : (sc == 1) ? 16 : 32;
            int S    = (sc == 2) ? 8 : 16;
            float v[4];
#pragma unroll
            for (int j = 0; j < 4; j++) {
                int ii = lane + j * 64;
                v[j] = (ii < C) ? final_all[off + b * C + ii] : -INFINITY;
            }
            for (int s = 0; s < S; s++) {
                float bd = v[0]; int bj = 0;
#pragma unroll
                for (int j = 1; j < 4; j++) if (v[j] > bd) { bd = v[j]; bj = j; }
                int bi2 = lane + bj * 64;
                float m = wred_max_f32(bd);
                int cand = (bd == m) ? bi2 : 0x7fffffff;
                int wi = wred_min_i32(cand);         // first-index tie-break
                if (lane == (wi & 63)) {
#pragma unroll
                    for (int j = 0; j < 4; j++) if (j == (wi >> 6)) v[j] = -INFINITY;
                }
                if (lane == 0) tokp[base + s] = idx_all[off + b * C + wi];
            }
        }
        __syncthreads();

        if (t < 320) {
            int tk = t % 40, jr = t / 40;   // jr 0..7
            int j = js * 8 + jr;
            int p = tokp[tk];
            const float* x = feat + ((size_t)b * N_PTS + p) * D_FEAT;
            const float* wrow = pW1 + (size_t)j * 768;
            float4 a = make_float4(0, 0, 0, 0);
            for (int k = 0; k < 768; k += 4) {
                float4 wv = *(const float4*)&wrow[k];
                float4 xv = *(const float4*)&x[k];
                a.x = fmaf(wv.x, xv.x, a.x); a.y = fmaf(wv.y, xv.y, a.y);
                a.z = fmaf(wv.z, xv.z, a.z); a.w = fmaf(wv.w, xv.w, a.w);
            }
            float v = (a.x + a.y) + (a.z + a.w) + pb1[j];
            h_buf[((size_t)b * 40 + tk) * 384 + j] = fmaxf(v, 0.f);
        }
    }
    grid.sync();

    // ================= phase 3: out GEMM + LayerNorm (blocks < 80) =================
    if (bid < 80) {
        float* hs = smem;                   // 384
        float* red = smem + 384;            // 8
        const float* hrow = h_buf + (size_t)bid * 384;
        for (int u = t; u < 384; u += 512) hs[u] = hrow[u];
        __syncthreads();

        float vout[3];
        if (t < 256) {
#pragma unroll
            for (int a = 0; a < 3; a++) {
                int o = t + a * 256;
                const float* wrow = pW2 + (size_t)o * 384;
                float4 acc = make_float4(0, 0, 0, 0);
                for (int k = 0; k < 384; k += 4) {
                    float4 wv = *(const float4*)&wrow[k];
                    float4 hv = *(const float4*)&hs[k];
                    acc.x = fmaf(wv.x, hv.x, acc.x); acc.y = fmaf(wv.y, hv.y, acc.y);
                    acc.z = fmaf(wv.z, hv.z, acc.z); acc.w = fmaf(wv.w, hv.w, acc.w);
                }
                vout[a] = (acc.x + acc.y) + (acc.z + acc.w) + pb2[o];
            }
            float s1 = (vout[0] + vout[1]) + vout[2];
            float s2 = (vout[0] * vout[0] + vout[1] * vout[1]) + vout[2] * vout[2];
            s1 = wred_add_f32(s1);
            s2 = wred_add_f32(s2);
            if (lane == 0) { red[w * 2] = s1; red[w * 2 + 1] = s2; }
        }
        __syncthreads();
        if (t < 256) {
            float S1 = (red[0] + red[2]) + (red[4] + red[6]);
            float S2 = (red[1] + red[3]) + (red[5] + red[7]);
            float mu = S1 / 768.0f;
            float var = S2 / 768.0f - mu * mu;
            float inv = rsqrtf(var + 1e-5f);
            float* dst = out + (size_t)bid * 768;
#pragma unroll
            for (int a = 0; a < 3; a++) {
                int o = t + a * 256;
                dst[o] = (vout[a] - mu) * inv * lng[o] + lnb[o];
            }
        }
    }
}

extern "C" void kernel_launch(void* const* d_in, const int* in_sizes, int n_in,
                              void* d_out, int out_size, void* d_ws, size_t ws_size,
                              hipStream_t stream) {
    const float* feat   = (const float*)d_in[0];
    const float* coords = (const float*)d_in[1];
    const float* gW1 = (const float*)d_in[2],  *gb1 = (const float*)d_in[3];
    const float* gW2 = (const float*)d_in[4],  *gb2 = (const float*)d_in[5];
    const float* cW1 = (const float*)d_in[6],  *cb1 = (const float*)d_in[7];
    const float* cW2 = (const float*)d_in[8],  *cb2 = (const float*)d_in[9];
    const float* dW1 = (const float*)d_in[10], *db1 = (const float*)d_in[11];
    const float* dW2 = (const float*)d_in[12], *db2 = (const float*)d_in[13];
    const float* pW1 = (const float*)d_in[14], *pb1 = (const float*)d_in[15];
    const float* pW2 = (const float*)d_in[16], *pb2 = (const float*)d_in[17];
    const float* lng = (const float*)d_in[18], *lnb = (const float*)d_in[19];
    float* out = (float*)d_out;

    int*   idx_all    = (int*)d_ws;               // 896 ints
    float* safety_all = (float*)d_ws + 896;       // 768 floats used
    float* final_all  = (float*)d_ws + 1792;      // 896 floats
    float* h_buf      = (float*)d_ws + 2688;      // 80*384 = 30720 floats

    void* args[] = {&feat, &coords, &gW1, &gb1, &gW2, &gb2, &cW1, &cb1, &cW2, &cb2,
                    &dW1, &db1, &dW2, &db2, &pW1, &pb1, &pW2, &pb2, &lng, &lnb,
                    &out, &idx_all, &safety_all, &final_all, &h_buf};
    hipLaunchCooperativeKernel((void*)mega_kernel, dim3(112), dim3(512), args, 0, stream);
}

// Round 9
// 532.542 us; speedup vs baseline: 1.1913x; 1.1913x over previous
//
#include <hip/hip_runtime.h>
#include <math.h>

#define N_PTS 8192
#define D_FEAT 768

typedef float v2f __attribute__((ext_vector_type(2)));

// ---- wave64 reductions via DPP (row_shr 1,2,4,8 + row_bcast15, row_bcast31) ----
__device__ __forceinline__ float wred_max_f32(float x) {   // x >= 0 required (identity 0)
    int v = __float_as_int(x), o;
    o = __builtin_amdgcn_update_dpp(0, v, 0x111, 0xf, 0xf, false); v = __float_as_int(fmaxf(__int_as_float(v), __int_as_float(o)));
    o = __builtin_amdgcn_update_dpp(0, v, 0x112, 0xf, 0xf, false); v = __float_as_int(fmaxf(__int_as_float(v), __int_as_float(o)));
    o = __builtin_amdgcn_update_dpp(0, v, 0x114, 0xf, 0xf, false); v = __float_as_int(fmaxf(__int_as_float(v), __int_as_float(o)));
    o = __builtin_amdgcn_update_dpp(0, v, 0x118, 0xf, 0xf, false); v = __float_as_int(fmaxf(__int_as_float(v), __int_as_float(o)));
    o = __builtin_amdgcn_update_dpp(0, v, 0x142, 0xa, 0xf, false); v = __float_as_int(fmaxf(__int_as_float(v), __int_as_float(o)));
    o = __builtin_amdgcn_update_dpp(0, v, 0x143, 0xc, 0xf, false); v = __float_as_int(fmaxf(__int_as_float(v), __int_as_float(o)));
    return __int_as_float(__builtin_amdgcn_readlane(v, 63));
}
__device__ __forceinline__ int wred_min_i32(int x) {       // x >= 0 (identity INT_MAX)
    int v = x, o;
    o = __builtin_amdgcn_update_dpp(0x7fffffff, v, 0x111, 0xf, 0xf, false); v = (o < v) ? o : v;
    o = __builtin_amdgcn_update_dpp(0x7fffffff, v, 0x112, 0xf, 0xf, false); v = (o < v) ? o : v;
    o = __builtin_amdgcn_update_dpp(0x7fffffff, v, 0x114, 0xf, 0xf, false); v = (o < v) ? o : v;
    o = __builtin_amdgcn_update_dpp(0x7fffffff, v, 0x118, 0xf, 0xf, false); v = (o < v) ? o : v;
    o = __builtin_amdgcn_update_dpp(0x7fffffff, v, 0x142, 0xa, 0xf, false); v = (o < v) ? o : v;
    o = __builtin_amdgcn_update_dpp(0x7fffffff, v, 0x143, 0xc, 0xf, false); v = (o < v) ? o : v;
    return __builtin_amdgcn_readlane(v, 63);
}
__device__ __forceinline__ float wred_add_f32(float x) {   // identity 0
    int v = __float_as_int(x), o;
    o = __builtin_amdgcn_update_dpp(0, v, 0x111, 0xf, 0xf, false); v = __float_as_int(__int_as_float(v) + __int_as_float(o));
    o = __builtin_amdgcn_update_dpp(0, v, 0x112, 0xf, 0xf, false); v = __float_as_int(__int_as_float(v) + __int_as_float(o));
    o = __builtin_amdgcn_update_dpp(0, v, 0x114, 0xf, 0xf, false); v = __float_as_int(__int_as_float(v) + __int_as_float(o));
    o = __builtin_amdgcn_update_dpp(0, v, 0x118, 0xf, 0xf, false); v = __float_as_int(__int_as_float(v) + __int_as_float(o));
    o = __builtin_amdgcn_update_dpp(0, v, 0x142, 0xa, 0xf, false); v = __float_as_int(__int_as_float(v) + __int_as_float(o));
    o = __builtin_amdgcn_update_dpp(0, v, 0x143, 0xc, 0xf, false); v = __float_as_int(__int_as_float(v) + __int_as_float(o));
    return __int_as_float(__builtin_amdgcn_readlane(v, 63));
}

// u64 max-merge DPP step: compiler lowers the compare to one v_cmp_lt_u64.
#define DPP64_STEP(cur, ctrl, rmask)                                                        \
    {                                                                                       \
        unsigned _h = (unsigned)__builtin_amdgcn_update_dpp(0, (int)(unsigned)((cur) >> 32), ctrl, rmask, 0xf, false); \
        unsigned _l = (unsigned)__builtin_amdgcn_update_dpp(0, (int)(unsigned)(cur), ctrl, rmask, 0xf, false);         \
        unsigned long long _o = ((unsigned long long)_h << 32) | _l;                        \
        cur = (_o > (cur)) ? _o : (cur);                                                    \
    }

// ---------------- FPS + global/component safety: one block per batch ----------------
// (r7 kernel verbatim -- 297 us plateau; 2 waves/SIMD, packed v2f update,
// merged guard/match predicate, DPP64 key chain, LDS coord table)
__global__ __launch_bounds__(512, 2) __attribute__((amdgpu_waves_per_eu(2)))
void fps_kernel(const float* __restrict__ coords,
                int* __restrict__ idx_all,
                float* __restrict__ safety_all) {
#pragma clang fp contract(off)
    const int b = blockIdx.x;         // 0..1
    const int t = threadIdx.x;        // 0..511
    const float* cb = coords + (size_t)b * N_PTS * 3;

    v2f px2[8], py2[8], pz2[8], m2p[8];
#pragma unroll
    for (int j = 0; j < 8; j++) {
        int p0 = t + (2 * j) * 512, p1 = t + (2 * j + 1) * 512;
        px2[j].x = cb[p0 * 3 + 0]; px2[j].y = cb[p1 * 3 + 0];
        py2[j].x = cb[p0 * 3 + 1]; py2[j].y = cb[p1 * 3 + 1];
        pz2[j].x = cb[p0 * 3 + 2]; pz2[j].y = cb[p1 * 3 + 2];
        m2p[j].x = INFINITY; m2p[j].y = INFINITY;
    }
    __shared__ float cbl4[N_PTS * 4];           // 128 KiB coord table, float4 stride
    __shared__ unsigned long long skey[2][8];
    __shared__ int sel[256];
    __shared__ float r1s[8], r2s[8];
#pragma unroll
    for (int j = 0; j < 8; j++) {
        int p0 = t + (2 * j) * 512, p1 = t + (2 * j + 1) * 512;
        *(float4*)&cbl4[p0 * 4] = make_float4(px2[j].x, py2[j].x, pz2[j].x, 0.f);
        *(float4*)&cbl4[p1 * 4] = make_float4(px2[j].y, py2[j].y, pz2[j].y, 0.f);
    }
    if (t == 0) sel[0] = 0;
    float lx = cb[0], ly = cb[1], lz = cb[2];   // center 0 (uniform broadcast load)
    __syncthreads();

    const int lane = t & 63, w = t >> 6;        // wave 0..7
    for (int i = 1; i < 256; i++) {
        // --- branch-free d2-domain update, packed f32x2 (numpy op order per half) ---
        v2f Lx = {lx, lx}, Ly = {ly, ly}, Lz = {lz, lz};
#pragma unroll
        for (int j = 0; j < 8; j++) {
            v2f dx = px2[j] - Lx, dy = py2[j] - Ly, dz = pz2[j] - Lz;
            v2f d2 = dx * dx + dy * dy + dz * dz;      // ((dx^2+dy^2)+dz^2), no fma
            m2p[j] = __builtin_elementwise_min(m2p[j], d2);
        }
        // --- per-thread max via balanced tree (order-independent for non-NaN) ---
        v2f q[4];
#pragma unroll
        for (int j = 0; j < 4; j++) q[j] = __builtin_elementwise_max(m2p[j], m2p[j + 4]);
        q[0] = __builtin_elementwise_max(q[0], q[2]);
        q[1] = __builtin_elementwise_max(q[1], q[3]);
        q[0] = __builtin_elementwise_max(q[0], q[1]);
        float c2 = fmaxf(q[0].x, q[0].y);
        float smax = sqrtf(c2);       // hoisted: latency hides under match/guard
        // --- merged guard + first-index match: one predicate set ---
        float thi = c2 * 0.9999995f;
        int tot = 0;
        int ci[8];
#pragma unroll
        for (int j = 0; j < 8; j++) {
            bool bx = (m2p[j].x >= thi);
            bool by = (m2p[j].y >= thi);
            tot += __popcll(__ballot(bx));
            tot += __popcll(__ballot(by));
            int a  = bx ? (2 * j)     : 0x7fff;
            int bb = by ? (2 * j + 1) : 0x7fff;
            ci[j] = (a < bb) ? a : bb;
        }
#pragma unroll
        for (int j = 0; j < 4; j++) ci[j] = min(ci[j], ci[j + 4]);
        int bk = min(min(ci[0], ci[1]), min(ci[2], ci[3]));
        if (tot > 64) {               // rare wave-uniform slow path (exact)
            smax = -1.f; bk = 0;
#pragma unroll
            for (int k = 0; k < 16; k++) {
                float mk = (k & 1) ? m2p[k >> 1].y : m2p[k >> 1].x;   // static idx (unrolled)
                float s = sqrtf(mk);
                if (s > smax) { smax = s; bk = k; }
            }
        }
        int bi = t + bk * 512;
        // --- wave reduce on packed u64 key: (value desc, index asc) ---
        unsigned long long key = ((unsigned long long)__float_as_uint(smax) << 32)
                               | (unsigned)(0xFFFFFFFFu - (unsigned)bi);
        DPP64_STEP(key, 0x111, 0xf)    // row_shr1
        DPP64_STEP(key, 0x112, 0xf)    // row_shr2
        DPP64_STEP(key, 0x114, 0xf)    // row_shr4
        DPP64_STEP(key, 0x118, 0xf)    // row_shr8
        DPP64_STEP(key, 0x142, 0xa)    // row_bcast15
        DPP64_STEP(key, 0x143, 0xc)    // row_bcast31
        if (lane == 63) skey[i & 1][w] = key;
        __syncthreads();   // LDS-only before barrier -> cheap lgkm drain
        const int par = i & 1;
        // --- read 8 wave records; speculatively load ALL candidates' coords (LDS) ---
        unsigned long long k8 = skey[par][lane & 7];
        int cidx = (int)(0xFFFFFFFFu - (unsigned)k8);   // candidate of record lane&7
        float spec = 0.f;
        if (lane < 24) spec = cbl4[cidx * 4 + (lane >> 3)];  // ds_read, covers 8x xyz
        // --- combine over 8 records (overlaps the LDS load) ---
        DPP64_STEP(k8, 0x111, 0xf)
        DPP64_STEP(k8, 0x112, 0xf)
        DPP64_STEP(k8, 0x114, 0xf)     // lane 7 = max of records 0..7
        unsigned klo = (unsigned)__builtin_amdgcn_readlane((int)(unsigned)k8, 7);
        int fbi = (int)(0xFFFFFFFFu - klo);             // uniform (SGPR)
        int ww = (fbi & 511) >> 6;                      // winning wave / record 0..7
        // winner coords from the speculative lanes: rec=ww, comp c at lane c*8+ww
        lx = __int_as_float(__builtin_amdgcn_readlane(__float_as_int(spec), ww));
        ly = __int_as_float(__builtin_amdgcn_readlane(__float_as_int(spec), 8 + ww));
        lz = __int_as_float(__builtin_amdgcn_readlane(__float_as_int(spec), 16 + ww));
        if (t == 0) sel[i] = fbi;     // LDS only
        // NOTE: no explicit zeroing of the winner: next update gives d2=0 exactly.
    }

    // ---- tail: write indices once (oc/od are prefixes of og) ----
    __syncthreads();
    if (t < 256) {
        int v = sel[t];
        idx_all[b * 256 + t] = v;                    // og
        if (t < 128) idx_all[512 + b * 128 + t] = v; // oc
        if (t < 64)  idx_all[768 + b * 64 + t] = v;  // od
    }

    // ---- tail: global & component safety (z in registers; k-order per thread) ----
    float s1 = 0.f, s2 = 0.f;
#pragma unroll
    for (int j = 0; j < 8; j++) {
        s1 += pz2[j].x; s2 += pz2[j].x * pz2[j].x;   // k = 2j
        s1 += pz2[j].y; s2 += pz2[j].y * pz2[j].y;   // k = 2j+1
    }
    s1 = wred_add_f32(s1);
    s2 = wred_add_f32(s2);
    if (lane == 0) { r1s[w] = s1; r2s[w] = s2; }
    __syncthreads();
    float S1 = ((r1s[0] + r1s[1]) + (r1s[2] + r1s[3])) + ((r1s[4] + r1s[5]) + (r1s[6] + r1s[7]));
    float S2 = ((r2s[0] + r2s[1]) + (r2s[2] + r2s[3])) + ((r2s[4] + r2s[5]) + (r2s[6] + r2s[7]));
    float mean = S1 / 8192.0f;
    float var1 = (S2 - S1 * S1 / 8192.0f) / 8191.0f;     // ddof=1
    float scomp = 1.0f + expf(-var1 / 0.1f) * 0.9f;      // component safety
    if (t < 256) {
        int p = sel[t];
        float z = cbl4[p * 4 + 2];                       // bit-identical copy of cb[p*3+2]
        safety_all[b * 256 + t] = 1.0f + (1.0f / (1.0f + expf(-((z - mean) / 5.0f)))) * 0.95f;
        if (t < 128) safety_all[512 + b * 128 + t] = scomp;
    }
}

// ---------------- per-scale score MLP (+ detail density folded in) ----------------
// ROUND 17: conflict-free W1 GEMM. Mega-kernel profiling (r8) exposed 2.4M LDS
// bank-conflict cycles in this phase: the old mapping (rp = t&7) put the 8
// rp-chunks of xt on ONE bank (96 % 32banks == 0 -> 8-way read conflict on
// every ds_read_b128) and collapsed part writes to a single bank (64-way).
// New mapping: rp = WAVE id (t>>6), jg = lane (t&63):
//  - xv reads are wave-uniform LDS addresses -> hardware broadcast, 0 conflicts
//  - part layout [rp][jg*PT + a*8 + r], PT = RT*8+1 (odd pad) -> write bank =
//    (jg*PT + 8a + r) % 32 spreads 64 lanes over 32 banks, 2/bank = free.
// Partial VALUES per rp-chunk and the balanced sum tree are bit-identical to
// r7 -> same outputs. W1 still read exactly once per block.
#define W1_GEMM(RT)                                                            \
  {                                                                            \
    const int jg = t & 63, rp = t >> 6;  /* rp uniform per wave */             \
    const int PT = RT * 8 + 1;                                                 \
    const float* wb = W1 + (size_t)(jg * RT) * 768 + rp * 96;                  \
    float4 acc[RT][8];                                                         \
    _Pragma("unroll") for (int a = 0; a < RT; a++)                             \
      _Pragma("unroll") for (int r = 0; r < 8; r++)                            \
        acc[a][r] = make_float4(0.f, 0.f, 0.f, 0.f);                           \
    for (int s = 0; s < 96; s += 4) {                                          \
      float4 xv[8];                                                            \
      _Pragma("unroll") for (int r = 0; r < 8; r++)                            \
        xv[r] = *(const float4*)&xt[r * 772 + rp * 96 + s];  /* uniform */     \
      _Pragma("unroll") for (int a = 0; a < RT; a++) {                         \
        float4 wv = *(const float4*)&wb[(size_t)a * 768 + s];                  \
        _Pragma("unroll") for (int r = 0; r < 8; r++) {                        \
          acc[a][r].x = fmaf(wv.x, xv[r].x, acc[a][r].x);                      \
          acc[a][r].y = fmaf(wv.y, xv[r].y, acc[a][r].y);                      \
          acc[a][r].z = fmaf(wv.z, xv[r].z, acc[a][r].z);                      \
          acc[a][r].w = fmaf(wv.w, xv[r].w, acc[a][r].w);                      \
        }                                                                      \
      }                                                                        \
    }                                                                          \
    _Pragma("unroll") for (int a = 0; a < RT; a++)                             \
      _Pragma("unroll") for (int r = 0; r < 8; r++)                            \
        part[rp * 64 * PT + jg * PT + a * 8 + r] =                             \
            (acc[a][r].x + acc[a][r].y) + (acc[a][r].z + acc[a][r].w);         \
    __syncthreads();                                                           \
    for (int u = t; u < (RT * 64) * 8; u += 512) {                             \
      int row = u >> 3, r = u & 7;                                             \
      int base = (row / RT) * PT + (row % RT) * 8 + r;                         \
      float sum = ((part[base] + part[64 * PT + base])                         \
                 + (part[2 * 64 * PT + base] + part[3 * 64 * PT + base]))      \
                + ((part[4 * 64 * PT + base] + part[5 * 64 * PT + base])       \
                 + (part[6 * 64 * PT + base] + part[7 * 64 * PT + base]))      \
                + b1[row];                                                     \
      h1s[r * 260 + row] = fmaxf(sum, 0.f);                                    \
    }                                                                          \
  }

__global__ __launch_bounds__(512) void score_kernel(
    const float* __restrict__ feat, const float* __restrict__ coords,
    const float* __restrict__ gW1, const float* __restrict__ gb1,
    const float* __restrict__ gW2, const float* __restrict__ gb2,
    const float* __restrict__ cW1, const float* __restrict__ cb1,
    const float* __restrict__ cW2, const float* __restrict__ cb2,
    const float* __restrict__ dW1, const float* __restrict__ db1,
    const float* __restrict__ dW2, const float* __restrict__ db2,
    const int* __restrict__ idx_all, const float* __restrict__ safety_all,
    float* __restrict__ final_all) {
    int bid = blockIdx.x;
    int b, c0, C, S, off;
    const float *W1, *b1, *W2, *b2;
    if (bid < 64)      { C = 256; S = 16; W1 = gW1; b1 = gb1; W2 = gW2; b2 = gb2; b = bid >> 5; c0 = (bid & 31) * 8; off = 0; }
    else if (bid < 96) { int r = bid - 64; C = 128; S = 16; W1 = cW1; b1 = cb1; W2 = cW2; b2 = cb2; b = r >> 4; c0 = (r & 15) * 8; off = 512; }
    else               { int r = bid - 96; C = 64;  S = 8;  W1 = dW1; b1 = db1; W2 = dW2; b2 = db2; b = r >> 3; c0 = (r & 7) * 8; off = 768; }
    const bool isdet = (bid >= 96);

    __shared__ float xt[8 * 772];        // 24.7 KB
    __shared__ float h1s[8 * 260];       // 8.3 KB
    __shared__ float part[8 * 2112];     // 67.6 KB  (max: RT=4 -> PT=33, 8*64*33)
    __shared__ float ps[8 * 16];
    __shared__ int pid[8];
    __shared__ float dpart[8][8];
    __shared__ float sdens[8];
    const int t = threadIdx.x;           // 0..511
    if (t < 8) pid[t] = idx_all[off + b * C + c0 + t];
    __syncthreads();

    if (isdet) {
#pragma clang fp contract(off)
        float cx[8], cy[8], cz[8], cc[8];
#pragma unroll
        for (int c = 0; c < 8; c++) {
            const float* cp = coords + ((size_t)b * N_PTS + pid[c]) * 3;
            cx[c] = cp[0]; cy[c] = cp[1]; cz[c] = cp[2];
            cc[c] = cx[c] * cx[c] + cy[c] * cy[c] + cz[c] * cz[c];
        }
        int cnt[8];
#pragma unroll
        for (int c = 0; c < 8; c++) cnt[c] = 0;
        const float* cbl = coords + (size_t)b * N_PTS * 3;
        for (int k = 0; k < 16; k++) {
            int q = t + k * 512;
            float x = cbl[q * 3], y = cbl[q * 3 + 1], z = cbl[q * 3 + 2];
            float pp = x * x + y * y + z * z;
#pragma unroll
            for (int c = 0; c < 8; c++) {
                float dot = cx[c] * x + cy[c] * y + cz[c] * z;
                float d2 = (cc[c] + pp) - 2.0f * dot;   // same formula/order as reference
                if (d2 < 0.25f) cnt[c]++;
            }
        }
        int wv = t >> 6;
#pragma unroll
        for (int c = 0; c < 8; c++) {
            float s = wred_add_f32((float)cnt[c]);      // integer counts: exact in f32
            if ((t & 63) == 0) dpart[wv][c] = s;
        }
    }

    for (int r = 0; r < 8; r++) {
        const float* src = feat + ((size_t)b * N_PTS + pid[r]) * D_FEAT;
        for (int c = t; c < 768; c += 512) xt[r * 772 + c] = src[c];
    }
    __syncthreads();
    if (isdet && t < 8) {
        // integer counts: exact in f32 regardless of summation order
        float tot = ((dpart[0][t] + dpart[1][t]) + (dpart[2][t] + dpart[3][t]))
                  + ((dpart[4][t] + dpart[5][t]) + (dpart[6][t] + dpart[7][t]));
        sdens[t] = 1.0f + (tot / 8192.0f) * 0.95f;
    }

    if (C == 256)      W1_GEMM(4)
    else if (C == 128) W1_GEMM(2)
    else               W1_GEMM(1)
    __syncthreads();

    if (t < 8 * S) {
        int r = t / S, s = t % S;
        float4 a = make_float4(0, 0, 0, 0);
        for (int k = 0; k < C; k += 4) {
            float4 wv = *(const float4*)&W2[s * C + k];
            float4 h = *(const float4*)&h1s[r * 260 + k];
            a.x = fmaf(wv.x, h.x, a.x); a.y = fmaf(wv.y, h.y, a.y);
            a.z = fmaf(wv.z, h.z, a.z); a.w = fmaf(wv.w, h.w, a.w);
        }
        float logit = (a.x + a.y) + (a.z + a.w) + b2[s];
        ps[r * 16 + s] = 1.0f / (1.0f + expf(-logit));
    }
    __syncthreads();
    if (t < 8) {
        float m = 0.f;
        for (int s = 0; s < S; s++) m += ps[t * 16 + s];
        m /= (float)S;
        float saf = isdet ? sdens[t] : safety_all[off + b * C + c0 + t];
        final_all[off + b * C + c0 + t] = m * saf;
    }
}

// ---------------- fused topk + h GEMM ----------------
__global__ __launch_bounds__(320) void hk_kernel(
    const float* __restrict__ feat, const int* __restrict__ idx_all,
    const float* __restrict__ final_all,
    const float* __restrict__ pW1, const float* __restrict__ pb1,
    float* __restrict__ h_buf) {
    int bid = blockIdx.x;               // 96 = 2 batches x 48 j-slices
    int b = bid / 48, js = bid % 48;
    int t = threadIdx.x;                // 320
    __shared__ int tokp[40];
    int w = t >> 6, lane = t & 63;
    if (w < 3) {                        // wave w does scale w's top-k
        int sc = w;
        int C    = (sc == 0) ? 256 : (sc == 1) ? 128 : 64;
        int off  = (sc == 0) ? 0 : (sc == 1) ? 512 : 768;
        int base = (sc == 0) ? 0 : (sc == 1) ? 16 : 32;
        int S    = (sc == 2) ? 8 : 16;
        float v[4];
#pragma unroll
        for (int j = 0; j < 4; j++) {
            int ii = lane + j * 64;
            v[j] = (ii < C) ? final_all[off + b * C + ii] : -INFINITY;
        }
        for (int s = 0; s < S; s++) {
            float bd = v[0]; int bj = 0;
#pragma unroll
            for (int j = 1; j < 4; j++) if (v[j] > bd) { bd = v[j]; bj = j; }
            int bi2 = lane + bj * 64;
            float m = wred_max_f32(bd);          // scores > 0, identity 0 safe
            int cand = (bd == m) ? bi2 : 0x7fffffff;
            int wi = wred_min_i32(cand);         // first-index tie-break = lax.top_k
            if (lane == (wi & 63)) {
#pragma unroll
                for (int j = 0; j < 4; j++) if (j == (wi >> 6)) v[j] = -INFINITY;
            }
            if (lane == 0) tokp[base + s] = idx_all[off + b * C + wi];
        }
    }
    __syncthreads();

    int tk = t % 40, jr = t / 40;       // jr 0..7
    int j = js * 8 + jr;
    int p = tokp[tk];
    const float* x = feat + ((size_t)b * N_PTS + p) * D_FEAT;
    const float* wrow = pW1 + (size_t)j * 768;
    float4 a = make_float4(0, 0, 0, 0);
    for (int k = 0; k < 768; k += 4) {
        float4 wv = *(const float4*)&wrow[k];
        float4 xv = *(const float4*)&x[k];
        a.x = fmaf(wv.x, xv.x, a.x); a.y = fmaf(wv.y, xv.y, a.y);
        a.z = fmaf(wv.z, xv.z, a.z); a.w = fmaf(wv.w, xv.w, a.w);
    }
    float v = (a.x + a.y) + (a.z + a.w) + pb1[j];
    h_buf[((size_t)b * 40 + tk) * 384 + j] = fmaxf(v, 0.f);
}

// ---------------- fused out GEMM + LayerNorm: one block per token ----------------
__global__ __launch_bounds__(256) void outln_kernel(
    const float* __restrict__ h_buf,
    const float* __restrict__ pW2, const float* __restrict__ pb2,
    const float* __restrict__ lng, const float* __restrict__ lnb,
    float* __restrict__ out) {
    int bid = blockIdx.x;               // 80 = 2 batches x 40 tokens
    int t = threadIdx.x;                // 256
    __shared__ float hs[384];
    __shared__ float red[8];
    const float* hrow = h_buf + (size_t)bid * 384;
    for (int u = t; u < 384; u += 256) hs[u] = hrow[u];
    __syncthreads();

    float vout[3];
#pragma unroll
    for (int a = 0; a < 3; a++) {
        int o = t + a * 256;
        const float* wrow = pW2 + (size_t)o * 384;
        float4 acc = make_float4(0, 0, 0, 0);
        for (int k = 0; k < 384; k += 4) {
            float4 wv = *(const float4*)&wrow[k];
            float4 hv = *(const float4*)&hs[k];
            acc.x = fmaf(wv.x, hv.x, acc.x); acc.y = fmaf(wv.y, hv.y, acc.y);
            acc.z = fmaf(wv.z, hv.z, acc.z); acc.w = fmaf(wv.w, hv.w, acc.w);
        }
        vout[a] = (acc.x + acc.y) + (acc.z + acc.w) + pb2[o];
    }

    float s1 = (vout[0] + vout[1]) + vout[2];
    float s2 = (vout[0] * vout[0] + vout[1] * vout[1]) + vout[2] * vout[2];
    s1 = wred_add_f32(s1);
    s2 = wred_add_f32(s2);
    int lane = t & 63, wid = t >> 6;
    if (lane == 0) { red[wid * 2] = s1; red[wid * 2 + 1] = s2; }
    __syncthreads();
    float S1 = (red[0] + red[2]) + (red[4] + red[6]);
    float S2 = (red[1] + red[3]) + (red[5] + red[7]);
    float mu = S1 / 768.0f;
    float var = S2 / 768.0f - mu * mu;
    float inv = rsqrtf(var + 1e-5f);
    float* dst = out + (size_t)bid * 768;
#pragma unroll
    for (int a = 0; a < 3; a++) {
        int o = t + a * 256;
        dst[o] = (vout[a] - mu) * inv * lng[o] + lnb[o];
    }
}

extern "C" void kernel_launch(void* const* d_in, const int* in_sizes, int n_in,
                              void* d_out, int out_size, void* d_ws, size_t ws_size,
                              hipStream_t stream) {
    const float* feat   = (const float*)d_in[0];
    const float* coords = (const float*)d_in[1];
    const float* gW1 = (const float*)d_in[2],  *gb1 = (const float*)d_in[3];
    const float* gW2 = (const float*)d_in[4],  *gb2 = (const float*)d_in[5];
    const float* cW1 = (const float*)d_in[6],  *cb1 = (const float*)d_in[7];
    const float* cW2 = (const float*)d_in[8],  *cb2 = (const float*)d_in[9];
    const float* dW1 = (const float*)d_in[10], *db1 = (const float*)d_in[11];
    const float* dW2 = (const float*)d_in[12], *db2 = (const float*)d_in[13];
    const float* pW1 = (const float*)d_in[14], *pb1 = (const float*)d_in[15];
    const float* pW2 = (const float*)d_in[16], *pb2 = (const float*)d_in[17];
    const float* lng = (const float*)d_in[18], *lnb = (const float*)d_in[19];
    float* out = (float*)d_out;

    int*   idx_all    = (int*)d_ws;               // 896 ints
    float* safety_all = (float*)d_ws + 896;       // 768 floats used
    float* final_all  = (float*)d_ws + 1792;      // 896 floats
    float* h_buf      = (float*)d_ws + 2688;      // 80*384 = 30720 floats

    fps_kernel<<<2, 512, 0, stream>>>(coords, idx_all, safety_all);
    score_kernel<<<112, 512, 0, stream>>>(feat, coords, gW1, gb1, gW2, gb2, cW1, cb1, cW2, cb2,
                                          dW1, db1, dW2, db2, idx_all, safety_all, final_all);
    hk_kernel<<<96, 320, 0, stream>>>(feat, idx_all, final_all, pW1, pb1, h_buf);
    outln_kernel<<<80, 256, 0, stream>>>(h_buf, pW2, pb2, lng, lnb, out);
}